// Round 17
// baseline (466.634 us; speedup 1.0000x reference)
//
#include <hip/hip_runtime.h>
#include <math.h>

// N=100000 nodes, E=1600000 edges, features 128 -> 64 -> 64 -> 1.
// R17: two-phase CSR build. R16 falsified the nt-load theory (WRITE 72->67MB,
// dur 68->75us): csr line amplification is structural — a node's edges are
// spread across the whole dst stream, so its 64B line can't stay dirty long
// enough to merge. Fix: (A) k_bucket partitions edges into 8 dst-shard
// buckets (LDS-staged, full-line flushes; degree histogram fused), then
// (B) k_scatter streams each ~1.6MB bucket into its 800KB csr slice —
// working set ~2.5MB < 4MB L2, so scatter lines merge.
// NOTE: __launch_bounds__(256,4) is 0-for-4 on this harness — do not use.
// gemm2 K-loop needs `#pragma unroll 2` (full unroll -> 256 VGPR, occ 9%).
#define NN 100000
#define NE 1600000
#define NSHARD 8
#define SHARD_W (NN / NSHARD)   // 12500 exactly
#define BCAP 220000             // per-bucket pair capacity (mean 200k, 47 sigma)
#define SCAP 320                // LDS staging per bucket per chunk (mean 128, 18 sigma)

// bf16 helpers (manual, round-to-nearest-even; intermediates only)
__device__ inline unsigned f2bf(float f) {
    unsigned u = __float_as_uint(f);
    u += 0x7FFFu + ((u >> 16) & 1u);
    return u >> 16;
}
__device__ inline float bflo(unsigned v) { return __uint_as_float(v << 16); }
__device__ inline float bfhi(unsigned v) { return __uint_as_float(v & 0xFFFF0000u); }

// ---------------------------------------------------------------------------
// CSR build, phase 0: zero deg + bucket cursors.
// ---------------------------------------------------------------------------
__global__ void k_zero_deg(int* __restrict__ deg, int* __restrict__ pcur) {
    int i = blockIdx.x * 256 + threadIdx.x;
    if (i < NN) deg[i] = 0;
    if (i < NSHARD) pcur[i] = 0;
}

// ---------------------------------------------------------------------------
// Phase A: partition edges into 8 dst-shard buckets of (dst,src) pairs.
// LDS-staged; flushes are contiguous ~1KB runs per bucket -> full-line
// writes. Also fuses the degree histogram (replaces k_hist).
// Chunk = 1024 edges/block-iteration (4/thread).
// ---------------------------------------------------------------------------
__global__ __launch_bounds__(256) void k_bucket(
    const int* __restrict__ src, const int* __restrict__ dst,
    int* __restrict__ deg, int* __restrict__ pcur, int2* __restrict__ pairs) {
    __shared__ int2 sbuf[NSHARD][SCAP];
    __shared__ int scnt[NSHARD];
    __shared__ int sbase[NSHARD];
    int t = threadIdx.x;
    for (long cbase = (long)blockIdx.x * 1024; cbase < NE; cbase += (long)gridDim.x * 1024) {
        if (t < NSHARD) scnt[t] = 0;
        __syncthreads();
#pragma unroll
        for (int j = 0; j < 4; ++j) {
            int e = (int)cbase + j * 256 + t;
            if (e < NE) {
                int d = __builtin_nontemporal_load(&dst[e]);
                int s = __builtin_nontemporal_load(&src[e]);
                atomicAdd(&deg[d], 1);
                int b = d / SHARD_W;
                int slot = atomicAdd(&scnt[b], 1);
                if (slot < SCAP) {
                    sbuf[b][slot] = make_int2(d, s);
                } else {  // statistically unreachable slow path (correctness guard)
                    int pos = atomicAdd(&pcur[b], 1);
                    if (pos < BCAP) pairs[(long)b * BCAP + pos] = make_int2(d, s);
                }
            }
        }
        __syncthreads();
        if (t < NSHARD) {
            int c = scnt[t];
            if (c > SCAP) c = SCAP;
            sbase[t] = atomicAdd(&pcur[t], c);
            scnt[t] = c;
        }
        __syncthreads();
        for (int b = 0; b < NSHARD; ++b) {
            int c = scnt[b], bs = sbase[b];
            for (int i = t; i < c; i += 256)
                pairs[(long)b * BCAP + bs + i] = sbuf[b][i];
        }
        __syncthreads();
    }
}

__global__ void k_bsum(const int* __restrict__ deg, int* __restrict__ bsums) {
    __shared__ int s[256];
    int t = threadIdx.x;
    int i = blockIdx.x * 256 + t;
    s[t] = (i < NN) ? deg[i] : 0;
    __syncthreads();
    for (int off = 128; off > 0; off >>= 1) {
        if (t < off) s[t] += s[t + off];
        __syncthreads();
    }
    if (t == 0) bsums[blockIdx.x] = s[0];
}

// single block of 512 threads scans the 391 block sums (exclusive)
__global__ void k_scan512(const int* __restrict__ bsums, int* __restrict__ bscan) {
    __shared__ int s[512];
    int t = threadIdx.x;
    int v = (t < 391) ? bsums[t] : 0;
    s[t] = v;
    __syncthreads();
    for (int off = 1; off < 512; off <<= 1) {
        int x = (t >= off) ? s[t - off] : 0;
        __syncthreads();
        s[t] += x;
        __syncthreads();
    }
    bscan[t] = s[t] - v;  // exclusive
}

__global__ void k_rowptr(const int* __restrict__ deg, const int* __restrict__ bscan,
                         int* __restrict__ rowptr, int* __restrict__ cursor,
                         float* __restrict__ dis) {
    __shared__ int s[256];
    int t = threadIdx.x;
    int i = blockIdx.x * 256 + t;
    int d = (i < NN) ? deg[i] : 0;
    s[t] = d;
    __syncthreads();
    for (int off = 1; off < 256; off <<= 1) {
        int x = (t >= off) ? s[t - off] : 0;
        __syncthreads();
        s[t] += x;
        __syncthreads();
    }
    if (i < NN) {
        int rp = bscan[blockIdx.x] + s[t] - d;  // exclusive global prefix
        rowptr[i] = rp;
        cursor[i] = rp;
        dis[i] = rsqrtf((float)(d + 1));  // +1 self-loop; deg>=1 always
    }
    if (i == 0) rowptr[NN] = NE;
}

// ---------------------------------------------------------------------------
// Phase B: per-shard scatter from the contiguous bucket into the csr slice.
// Stream (1.6MB) + dirty csr slice (800KB) + cursor slice fit one XCD L2.
// ---------------------------------------------------------------------------
__global__ __launch_bounds__(256) void k_scatter(
    const int2* __restrict__ pairs, const int* __restrict__ pcur,
    int* __restrict__ cursor, int* __restrict__ csr) {
    int shard = blockIdx.x & 7;
    int n = pcur[shard];
    if (n > BCAP) n = BCAP;
    int stride = (gridDim.x >> 3) * 256;
    for (int i = (blockIdx.x >> 3) * 256 + threadIdx.x; i < n; i += stride) {
        int2 p = pairs[(long)shard * BCAP + i];
        int pos = atomicAdd(&cursor[p.x], 1);
        csr[pos] = p.y;
    }
}

// ---------------------------------------------------------------------------
// GEMM layer 1: tsb[row][c] = bf16( (sum_k x[row][k]*W[k][c]) * dis[row] )
// 64 rows x 64 cols per block; thread = 4 rows x 4 cols register tile.
// W and x staged as packed bf16 PAIRS in LDS (one pass, one barrier).
// ---------------------------------------------------------------------------
__global__ __launch_bounds__(256) void k_gemm1(
    const float* __restrict__ x, const float* __restrict__ W,
    const float* __restrict__ dis, unsigned short* __restrict__ tsb) {
    __shared__ unsigned Wsb[128 * 32];
    __shared__ unsigned xsb[64 * 66];
    int t = threadIdx.x;
    int row0 = blockIdx.x * 64;
    for (int i = t; i < 128 * 32; i += 256) {
        int k = i >> 5, c2 = i & 31;
        float2 wv = *(const float2*)&W[k * 64 + 2 * c2];
        Wsb[i] = f2bf(wv.x) | (f2bf(wv.y) << 16);
    }
    for (int i = t; i < 64 * 64; i += 256) {
        int r = i >> 6, k2 = i & 63;
        int gr = row0 + r;
        unsigned p = 0u;
        if (gr < NN) {
            float2 xv = *(const float2*)&x[gr * 128 + 2 * k2];
            p = f2bf(xv.x) | (f2bf(xv.y) << 16);
        }
        xsb[r * 66 + k2] = p;
    }
    __syncthreads();
    int cg = t & 15, rg = t >> 4;
    int col = cg * 4;
    float4 acc0 = {0, 0, 0, 0}, acc1 = {0, 0, 0, 0}, acc2 = {0, 0, 0, 0}, acc3 = {0, 0, 0, 0};
    for (int k2 = 0; k2 < 64; ++k2) {
        uint2 wa = *(const uint2*)&Wsb[(2 * k2) * 32 + cg * 2];
        uint2 wb = *(const uint2*)&Wsb[(2 * k2 + 1) * 32 + cg * 2];
        float wa0 = bflo(wa.x), wa1 = bfhi(wa.x), wa2 = bflo(wa.y), wa3 = bfhi(wa.y);
        float wb0 = bflo(wb.x), wb1 = bfhi(wb.x), wb2 = bflo(wb.y), wb3 = bfhi(wb.y);
        unsigned xp0 = xsb[(rg * 4 + 0) * 66 + k2];
        unsigned xp1 = xsb[(rg * 4 + 1) * 66 + k2];
        unsigned xp2 = xsb[(rg * 4 + 2) * 66 + k2];
        unsigned xp3 = xsb[(rg * 4 + 3) * 66 + k2];
        float xl, xh;
        xl = bflo(xp0); xh = bfhi(xp0);
        acc0.x += xl * wa0 + xh * wb0; acc0.y += xl * wa1 + xh * wb1;
        acc0.z += xl * wa2 + xh * wb2; acc0.w += xl * wa3 + xh * wb3;
        xl = bflo(xp1); xh = bfhi(xp1);
        acc1.x += xl * wa0 + xh * wb0; acc1.y += xl * wa1 + xh * wb1;
        acc1.z += xl * wa2 + xh * wb2; acc1.w += xl * wa3 + xh * wb3;
        xl = bflo(xp2); xh = bfhi(xp2);
        acc2.x += xl * wa0 + xh * wb0; acc2.y += xl * wa1 + xh * wb1;
        acc2.z += xl * wa2 + xh * wb2; acc2.w += xl * wa3 + xh * wb3;
        xl = bflo(xp3); xh = bfhi(xp3);
        acc3.x += xl * wa0 + xh * wb0; acc3.y += xl * wa1 + xh * wb1;
        acc3.z += xl * wa2 + xh * wb2; acc3.w += xl * wa3 + xh * wb3;
    }
    float4 accs[4] = {acc0, acc1, acc2, acc3};
#pragma unroll
    for (int r = 0; r < 4; ++r) {
        int row = row0 + rg * 4 + r;
        if (row < NN) {
            float dv = dis[row];
            float4 a = accs[r];
            uint2 p;
            p.x = f2bf(a.x * dv) | (f2bf(a.y * dv) << 16);
            p.y = f2bf(a.z * dv) | (f2bf(a.w * dv) << 16);
            *(uint2*)&tsb[row * 64 + col] = p;
        }
    }
}

#define FMA4(acc, xv)                                              \
    acc.x += xv.x * w0.x + xv.y * w1.x + xv.z * w2.x + xv.w * w3.x; \
    acc.y += xv.x * w0.y + xv.y * w1.y + xv.z * w2.y + xv.w * w3.y; \
    acc.z += xv.x * w0.z + xv.y * w1.z + xv.z * w2.z + xv.w * w3.z; \
    acc.w += xv.x * w0.w + xv.y * w1.w + xv.z * w2.w + xv.w * w3.w;

// GEMM layer 2: reads bf16 h, writes bf16 ts. K=64.
// K-loop capped at unroll 2: full unroll balloons to 256 VGPR (R13).
__global__ __launch_bounds__(256) void k_gemm2(
    const unsigned short* __restrict__ hb, const float* __restrict__ W,
    const float* __restrict__ dis, unsigned short* __restrict__ tsb) {
    __shared__ float Ws[64 * 64];
    __shared__ float hs[64 * 68];
    int t = threadIdx.x;
    int row0 = blockIdx.x * 64;
    for (int i = t; i < 64 * 64; i += 256) Ws[i] = W[i];
    const unsigned* hb32 = (const unsigned*)hb;  // 2 bf16 per word, row stride 32
    for (int i = t; i < 64 * 32; i += 256) {
        int r = i >> 5, c2 = i & 31;
        int gr = row0 + r;
        unsigned v = (gr < NN) ? hb32[gr * 32 + c2] : 0u;
        hs[r * 68 + 2 * c2] = bflo(v);
        hs[r * 68 + 2 * c2 + 1] = bfhi(v);
    }
    __syncthreads();
    int cg = t & 15, rg = t >> 4;
    int col = cg * 4;
    float4 acc0 = {0, 0, 0, 0}, acc1 = {0, 0, 0, 0}, acc2 = {0, 0, 0, 0}, acc3 = {0, 0, 0, 0};
#pragma unroll 2
    for (int k = 0; k < 64; k += 4) {
        float4 w0 = *(const float4*)&Ws[(k + 0) * 64 + col];
        float4 w1 = *(const float4*)&Ws[(k + 1) * 64 + col];
        float4 w2 = *(const float4*)&Ws[(k + 2) * 64 + col];
        float4 w3 = *(const float4*)&Ws[(k + 3) * 64 + col];
        float4 x0 = *(const float4*)&hs[(rg * 4 + 0) * 68 + k];
        float4 x1 = *(const float4*)&hs[(rg * 4 + 1) * 68 + k];
        float4 x2 = *(const float4*)&hs[(rg * 4 + 2) * 68 + k];
        float4 x3 = *(const float4*)&hs[(rg * 4 + 3) * 68 + k];
        FMA4(acc0, x0) FMA4(acc1, x1) FMA4(acc2, x2) FMA4(acc3, x3)
    }
    float4 accs[4] = {acc0, acc1, acc2, acc3};
#pragma unroll
    for (int r = 0; r < 4; ++r) {
        int row = row0 + rg * 4 + r;
        if (row < NN) {
            float dv = dis[row];
            float4 a = accs[r];
            uint2 p;
            p.x = f2bf(a.x * dv) | (f2bf(a.y * dv) << 16);
            p.y = f2bf(a.z * dv) | (f2bf(a.w * dv) << 16);
            *(uint2*)&tsb[row * 64 + col] = p;
        }
    }
}

// ---------------------------------------------------------------------------
// Fused aggregation + dis scale + bias + ReLU, bf16 rows (128 B each).
// One 64-lane wave per node; halves of the wave each gather one edge per
// load (lane = feature PAIR) -> 2 edges per wave instruction. f32 accum.
// ---------------------------------------------------------------------------
__global__ __launch_bounds__(256) void k_agg_relu(
    const unsigned short* __restrict__ tsb, const int* __restrict__ rowptr,
    const int* __restrict__ csr, const float* __restrict__ dis,
    const float* __restrict__ b, unsigned short* __restrict__ hb) {
    int node = blockIdx.x * 4 + (threadIdx.x >> 6);
    if (node >= NN) return;
    int lane = threadIdx.x & 63;
    int half = lane >> 5;
    int fl = lane & 31;  // feature pair: features 2*fl, 2*fl+1
    const unsigned* ts32 = (const unsigned*)tsb;  // row stride 32 words
    float ax = 0.f, ay = 0.f;
    if (half == 0) {  // self-loop term, added once
        unsigned v = ts32[node * 32 + fl];
        ax += bflo(v); ay += bfhi(v);
    }
    int e = rowptr[node] + half, end = rowptr[node + 1];
    for (; e + 2 < end; e += 4) {
        int s0 = csr[e];
        int s1 = csr[e + 2];
        unsigned v0 = ts32[s0 * 32 + fl];
        unsigned v1 = ts32[s1 * 32 + fl];
        ax += bflo(v0) + bflo(v1);
        ay += bfhi(v0) + bfhi(v1);
    }
    if (e < end) {
        unsigned v = ts32[csr[e] * 32 + fl];
        ax += bflo(v); ay += bfhi(v);
    }
    ax += __shfl_xor(ax, 32);
    ay += __shfl_xor(ay, 32);
    if (half == 0) {
        float dv = dis[node];
        float vx = fmaxf(ax * dv + b[2 * fl], 0.f);
        float vy = fmaxf(ay * dv + b[2 * fl + 1], 0.f);
        ((unsigned*)hb)[node * 32 + fl] = f2bf(vx) | (f2bf(vy) << 16);
    }
}

// ---------------------------------------------------------------------------
// Layer 3 projection: t3[row] = dot(h_bf16[row], W3) * dis[row]   (f32 out)
// ---------------------------------------------------------------------------
__global__ void k_gemm3(const unsigned short* __restrict__ hb, const float* __restrict__ W3,
                        const float* __restrict__ dis, float* __restrict__ t3) {
    __shared__ float Ws[64];
    if (threadIdx.x < 64) Ws[threadIdx.x] = W3[threadIdx.x];
    __syncthreads();
    int row = blockIdx.x * 256 + threadIdx.x;
    if (row >= NN) return;
    const uint4* hp = (const uint4*)(hb + row * 64);  // 8 x uint4 = 128 B
    float acc = 0.f;
#pragma unroll
    for (int k = 0; k < 8; ++k) {
        uint4 v = hp[k];
        acc += bflo(v.x) * Ws[8 * k + 0] + bfhi(v.x) * Ws[8 * k + 1]
             + bflo(v.y) * Ws[8 * k + 2] + bfhi(v.y) * Ws[8 * k + 3]
             + bflo(v.z) * Ws[8 * k + 4] + bfhi(v.z) * Ws[8 * k + 5]
             + bflo(v.w) * Ws[8 * k + 6] + bfhi(v.w) * Ws[8 * k + 7];
    }
    t3[row] = acc * dis[row];
}

// Fused layer-3 aggregation + sigmoid. One thread per node, scalar gathers.
__global__ void k_out(const float* __restrict__ t3, const int* __restrict__ rowptr,
                      const int* __restrict__ csr, const float* __restrict__ dis,
                      const float* __restrict__ b3, float* __restrict__ out) {
    int i = blockIdx.x * 256 + threadIdx.x;
    if (i >= NN) return;
    float acc = t3[i];
    float acc1 = 0.f;
    int e = rowptr[i], end = rowptr[i + 1];
    for (; e + 2 <= end; e += 2) {
        acc += t3[csr[e]];
        acc1 += t3[csr[e + 1]];
    }
    if (e < end) acc += t3[csr[e]];
    float z = (acc + acc1) * dis[i] + b3[0];
    out[i] = 1.f / (1.f + __expf(-z));
}

// ---------------------------------------------------------------------------
extern "C" void kernel_launch(void* const* d_in, const int* in_sizes, int n_in,
                              void* d_out, int out_size, void* d_ws, size_t ws_size,
                              hipStream_t stream) {
    const float* x  = (const float*)d_in[0];   // N x 128
    const float* W1 = (const float*)d_in[1];   // 128 x 64
    const float* b1 = (const float*)d_in[2];   // 64
    const float* W2 = (const float*)d_in[3];   // 64 x 64
    const float* b2 = (const float*)d_in[4];   // 64
    const float* W3 = (const float*)d_in[5];   // 64 x 1
    const float* b3 = (const float*)d_in[6];   // 1
    const int*   ei = (const int*)d_in[7];     // 2 x E
    const int* src = ei;
    const int* dst = ei + NE;
    float* out = (float*)d_out;

    // Workspace layout (pairs placed right after HB for 8B alignment)
    unsigned short* TSB = (unsigned short*)d_ws;          // N*64 bf16 (ts)
    unsigned short* HB  = TSB + (size_t)NN * 64;          // N*64 bf16 (h)
    int2*  pairs  = (int2*)(HB + (size_t)NN * 64);        // 8*BCAP int2 (14.1 MB)
    float* dis    = (float*)(pairs + (size_t)NSHARD * BCAP);  // N
    float* t3     = dis + NN;                             // N
    int*   deg    = (int*)(t3 + NN);                      // N
    int*   rowptr = deg + NN;                             // N+1 (+pad)
    int*   cursor = rowptr + NN + 8;                      // N
    int*   pcur   = cursor + NN;                          // 8 (+pad)
    int*   bsums  = pcur + 16;                            // 512
    int*   bscan  = bsums + 512;                          // 512
    int*   csr    = bscan + 512;                          // E

    const int nbN = (NN + 255) / 256;   // 391
    const int nbG = (NN + 63) / 64;     // 1563
    const int nbA = (NN + 3) / 4;       // 25000

    // CSR build + normalization (two-phase counting sort)
    k_zero_deg<<<nbN, 256, 0, stream>>>(deg, pcur);
    k_bucket<<<512, 256, 0, stream>>>(src, dst, deg, pcur, pairs);
    k_bsum<<<nbN, 256, 0, stream>>>(deg, bsums);
    k_scan512<<<1, 512, 0, stream>>>(bsums, bscan);
    k_rowptr<<<nbN, 256, 0, stream>>>(deg, bscan, rowptr, cursor, dis);
    k_scatter<<<2048, 256, 0, stream>>>(pairs, pcur, cursor, csr);

    // Layer 1
    k_gemm1<<<nbG, 256, 0, stream>>>(x, W1, dis, TSB);
    k_agg_relu<<<nbA, 256, 0, stream>>>(TSB, rowptr, csr, dis, b1, HB);

    // Layer 2
    k_gemm2<<<nbG, 256, 0, stream>>>(HB, W2, dis, TSB);
    k_agg_relu<<<nbA, 256, 0, stream>>>(TSB, rowptr, csr, dis, b2, HB);

    // Layer 3
    k_gemm3<<<nbN, 256, 0, stream>>>(HB, W3, dis, t3);
    k_out<<<nbN, 256, 0, stream>>>(t3, rowptr, csr, dis, b3, out);
}

// Round 18
// 436.852 us; speedup vs baseline: 1.0682x; 1.0682x over previous
//
#include <hip/hip_runtime.h>
#include <math.h>

// N=100000 nodes, E=1600000 edges, features 128 -> 64 -> 64 -> 1.
// R18 = R15 CSR build (reverted: R17's bucket approach lost 9us; ~51MB of its
// WRITE is fixed per-atomic transaction cost (~32B each) that no bucketing
// removes) + quarter-wave k_agg_relu (16 lanes x 8B per edge -> 4 edges in
// flight per load instruction, 2x MLP vs half-wave).
// NOTE: __launch_bounds__(256,4) is 0-for-4 on this harness — do not use.
// gemm2 K-loop needs `#pragma unroll 2` (full unroll -> 256 VGPR, occ 9%).
#define NN 100000
#define NE 1600000
#define NSHARD 8
#define SHARD_W (NN / NSHARD)   // 12500 exactly

// bf16 helpers (manual, round-to-nearest-even; intermediates only)
__device__ inline unsigned f2bf(float f) {
    unsigned u = __float_as_uint(f);
    u += 0x7FFFu + ((u >> 16) & 1u);
    return u >> 16;
}
__device__ inline float bflo(unsigned v) { return __uint_as_float(v << 16); }
__device__ inline float bfhi(unsigned v) { return __uint_as_float(v & 0xFFFF0000u); }

// ---------------------------------------------------------------------------
// CSR build: deg histogram -> block sums -> scan -> rowptr/cursor -> scatter.
// ---------------------------------------------------------------------------
__global__ void k_zero_deg(int* __restrict__ deg) {
    int i = blockIdx.x * 256 + threadIdx.x;
    if (i < NN) deg[i] = 0;
}

__global__ void k_hist(const int* __restrict__ dst, int* __restrict__ deg) {
    int e = blockIdx.x * 256 + threadIdx.x;
    if (e < NE) atomicAdd(&deg[dst[e]], 1);
}

__global__ void k_bsum(const int* __restrict__ deg, int* __restrict__ bsums) {
    __shared__ int s[256];
    int t = threadIdx.x;
    int i = blockIdx.x * 256 + t;
    s[t] = (i < NN) ? deg[i] : 0;
    __syncthreads();
    for (int off = 128; off > 0; off >>= 1) {
        if (t < off) s[t] += s[t + off];
        __syncthreads();
    }
    if (t == 0) bsums[blockIdx.x] = s[0];
}

// single block of 512 threads scans the 391 block sums (exclusive)
__global__ void k_scan512(const int* __restrict__ bsums, int* __restrict__ bscan) {
    __shared__ int s[512];
    int t = threadIdx.x;
    int v = (t < 391) ? bsums[t] : 0;
    s[t] = v;
    __syncthreads();
    for (int off = 1; off < 512; off <<= 1) {
        int x = (t >= off) ? s[t - off] : 0;
        __syncthreads();
        s[t] += x;
        __syncthreads();
    }
    bscan[t] = s[t] - v;  // exclusive
}

__global__ void k_rowptr(const int* __restrict__ deg, const int* __restrict__ bscan,
                         int* __restrict__ rowptr, int* __restrict__ cursor,
                         float* __restrict__ dis) {
    __shared__ int s[256];
    int t = threadIdx.x;
    int i = blockIdx.x * 256 + t;
    int d = (i < NN) ? deg[i] : 0;
    s[t] = d;
    __syncthreads();
    for (int off = 1; off < 256; off <<= 1) {
        int x = (t >= off) ? s[t - off] : 0;
        __syncthreads();
        s[t] += x;
        __syncthreads();
    }
    if (i < NN) {
        int rp = bscan[blockIdx.x] + s[t] - d;  // exclusive global prefix
        rowptr[i] = rp;
        cursor[i] = rp;
        dis[i] = rsqrtf((float)(d + 1));  // +1 self-loop; deg>=1 always
    }
    if (i == 0) rowptr[NN] = NE;
}

// XCD-sharded scatter (each shard's csr slice merges in one XCD's L2).
__global__ __launch_bounds__(256) void k_build_csr(
    const int* __restrict__ src, const int* __restrict__ dst,
    int* __restrict__ cursor, int* __restrict__ csr) {
    int shard = blockIdx.x & 7;
    int bsh = blockIdx.x >> 3;
    int stride = (gridDim.x >> 3) * 256;
    int lo = shard * SHARD_W;
    int hi = lo + SHARD_W;
    for (int e = bsh * 256 + threadIdx.x; e < NE; e += stride) {
        int d = dst[e];
        if (d >= lo && d < hi) {
            int pos = atomicAdd(&cursor[d], 1);
            csr[pos] = src[e];
        }
    }
}

// ---------------------------------------------------------------------------
// GEMM layer 1: tsb[row][c] = bf16( (sum_k x[row][k]*W[k][c]) * dis[row] )
// 64 rows x 64 cols per block; thread = 4 rows x 4 cols register tile.
// W and x staged as packed bf16 PAIRS in LDS (one pass, one barrier).
// ---------------------------------------------------------------------------
__global__ __launch_bounds__(256) void k_gemm1(
    const float* __restrict__ x, const float* __restrict__ W,
    const float* __restrict__ dis, unsigned short* __restrict__ tsb) {
    __shared__ unsigned Wsb[128 * 32];
    __shared__ unsigned xsb[64 * 66];
    int t = threadIdx.x;
    int row0 = blockIdx.x * 64;
    for (int i = t; i < 128 * 32; i += 256) {
        int k = i >> 5, c2 = i & 31;
        float2 wv = *(const float2*)&W[k * 64 + 2 * c2];
        Wsb[i] = f2bf(wv.x) | (f2bf(wv.y) << 16);
    }
    for (int i = t; i < 64 * 64; i += 256) {
        int r = i >> 6, k2 = i & 63;
        int gr = row0 + r;
        unsigned p = 0u;
        if (gr < NN) {
            float2 xv = *(const float2*)&x[gr * 128 + 2 * k2];
            p = f2bf(xv.x) | (f2bf(xv.y) << 16);
        }
        xsb[r * 66 + k2] = p;
    }
    __syncthreads();
    int cg = t & 15, rg = t >> 4;
    int col = cg * 4;
    float4 acc0 = {0, 0, 0, 0}, acc1 = {0, 0, 0, 0}, acc2 = {0, 0, 0, 0}, acc3 = {0, 0, 0, 0};
    for (int k2 = 0; k2 < 64; ++k2) {
        uint2 wa = *(const uint2*)&Wsb[(2 * k2) * 32 + cg * 2];
        uint2 wb = *(const uint2*)&Wsb[(2 * k2 + 1) * 32 + cg * 2];
        float wa0 = bflo(wa.x), wa1 = bfhi(wa.x), wa2 = bflo(wa.y), wa3 = bfhi(wa.y);
        float wb0 = bflo(wb.x), wb1 = bfhi(wb.x), wb2 = bflo(wb.y), wb3 = bfhi(wb.y);
        unsigned xp0 = xsb[(rg * 4 + 0) * 66 + k2];
        unsigned xp1 = xsb[(rg * 4 + 1) * 66 + k2];
        unsigned xp2 = xsb[(rg * 4 + 2) * 66 + k2];
        unsigned xp3 = xsb[(rg * 4 + 3) * 66 + k2];
        float xl, xh;
        xl = bflo(xp0); xh = bfhi(xp0);
        acc0.x += xl * wa0 + xh * wb0; acc0.y += xl * wa1 + xh * wb1;
        acc0.z += xl * wa2 + xh * wb2; acc0.w += xl * wa3 + xh * wb3;
        xl = bflo(xp1); xh = bfhi(xp1);
        acc1.x += xl * wa0 + xh * wb0; acc1.y += xl * wa1 + xh * wb1;
        acc1.z += xl * wa2 + xh * wb2; acc1.w += xl * wa3 + xh * wb3;
        xl = bflo(xp2); xh = bfhi(xp2);
        acc2.x += xl * wa0 + xh * wb0; acc2.y += xl * wa1 + xh * wb1;
        acc2.z += xl * wa2 + xh * wb2; acc2.w += xl * wa3 + xh * wb3;
        xl = bflo(xp3); xh = bfhi(xp3);
        acc3.x += xl * wa0 + xh * wb0; acc3.y += xl * wa1 + xh * wb1;
        acc3.z += xl * wa2 + xh * wb2; acc3.w += xl * wa3 + xh * wb3;
    }
    float4 accs[4] = {acc0, acc1, acc2, acc3};
#pragma unroll
    for (int r = 0; r < 4; ++r) {
        int row = row0 + rg * 4 + r;
        if (row < NN) {
            float dv = dis[row];
            float4 a = accs[r];
            uint2 p;
            p.x = f2bf(a.x * dv) | (f2bf(a.y * dv) << 16);
            p.y = f2bf(a.z * dv) | (f2bf(a.w * dv) << 16);
            *(uint2*)&tsb[row * 64 + col] = p;
        }
    }
}

#define FMA4(acc, xv)                                              \
    acc.x += xv.x * w0.x + xv.y * w1.x + xv.z * w2.x + xv.w * w3.x; \
    acc.y += xv.x * w0.y + xv.y * w1.y + xv.z * w2.y + xv.w * w3.y; \
    acc.z += xv.x * w0.z + xv.y * w1.z + xv.z * w2.z + xv.w * w3.z; \
    acc.w += xv.x * w0.w + xv.y * w1.w + xv.z * w2.w + xv.w * w3.w;

// GEMM layer 2: reads bf16 h, writes bf16 ts. K=64.
// K-loop capped at unroll 2: full unroll balloons to 256 VGPR (R13).
__global__ __launch_bounds__(256) void k_gemm2(
    const unsigned short* __restrict__ hb, const float* __restrict__ W,
    const float* __restrict__ dis, unsigned short* __restrict__ tsb) {
    __shared__ float Ws[64 * 64];
    __shared__ float hs[64 * 68];
    int t = threadIdx.x;
    int row0 = blockIdx.x * 64;
    for (int i = t; i < 64 * 64; i += 256) Ws[i] = W[i];
    const unsigned* hb32 = (const unsigned*)hb;  // 2 bf16 per word, row stride 32
    for (int i = t; i < 64 * 32; i += 256) {
        int r = i >> 5, c2 = i & 31;
        int gr = row0 + r;
        unsigned v = (gr < NN) ? hb32[gr * 32 + c2] : 0u;
        hs[r * 68 + 2 * c2] = bflo(v);
        hs[r * 68 + 2 * c2 + 1] = bfhi(v);
    }
    __syncthreads();
    int cg = t & 15, rg = t >> 4;
    int col = cg * 4;
    float4 acc0 = {0, 0, 0, 0}, acc1 = {0, 0, 0, 0}, acc2 = {0, 0, 0, 0}, acc3 = {0, 0, 0, 0};
#pragma unroll 2
    for (int k = 0; k < 64; k += 4) {
        float4 w0 = *(const float4*)&Ws[(k + 0) * 64 + col];
        float4 w1 = *(const float4*)&Ws[(k + 1) * 64 + col];
        float4 w2 = *(const float4*)&Ws[(k + 2) * 64 + col];
        float4 w3 = *(const float4*)&Ws[(k + 3) * 64 + col];
        float4 x0 = *(const float4*)&hs[(rg * 4 + 0) * 68 + k];
        float4 x1 = *(const float4*)&hs[(rg * 4 + 1) * 68 + k];
        float4 x2 = *(const float4*)&hs[(rg * 4 + 2) * 68 + k];
        float4 x3 = *(const float4*)&hs[(rg * 4 + 3) * 68 + k];
        FMA4(acc0, x0) FMA4(acc1, x1) FMA4(acc2, x2) FMA4(acc3, x3)
    }
    float4 accs[4] = {acc0, acc1, acc2, acc3};
#pragma unroll
    for (int r = 0; r < 4; ++r) {
        int row = row0 + rg * 4 + r;
        if (row < NN) {
            float dv = dis[row];
            float4 a = accs[r];
            uint2 p;
            p.x = f2bf(a.x * dv) | (f2bf(a.y * dv) << 16);
            p.y = f2bf(a.z * dv) | (f2bf(a.w * dv) << 16);
            *(uint2*)&tsb[row * 64 + col] = p;
        }
    }
}

// ---------------------------------------------------------------------------
// Fused aggregation + dis scale + bias + ReLU, bf16 rows (128 B each).
// One 64-lane wave per node; QUARTER-wave (16 lanes x 8B) per edge -> 4
// edges in flight per load instruction. lane = feature QUAD (uint2 = 4 bf16).
// f32 accumulation; quads combined via shfl_xor(16) + shfl_xor(32).
// ---------------------------------------------------------------------------
__global__ __launch_bounds__(256) void k_agg_relu(
    const unsigned short* __restrict__ tsb, const int* __restrict__ rowptr,
    const int* __restrict__ csr, const float* __restrict__ dis,
    const float* __restrict__ b, unsigned short* __restrict__ hb) {
    int node = blockIdx.x * 4 + (threadIdx.x >> 6);
    if (node >= NN) return;
    int lane = threadIdx.x & 63;
    int q = lane >> 4;    // quarter 0..3
    int fl = lane & 15;   // feature quad: features 4*fl .. 4*fl+3
    const uint2* ts64 = (const uint2*)tsb;  // row stride 16 uint2
    float a0 = 0.f, a1 = 0.f, a2 = 0.f, a3 = 0.f;
    if (q == 0) {  // self-loop term, added once
        uint2 v = ts64[node * 16 + fl];
        a0 += bflo(v.x); a1 += bfhi(v.x); a2 += bflo(v.y); a3 += bfhi(v.y);
    }
    int e = rowptr[node] + q, end = rowptr[node + 1];
    // per-quarter stride 4; unroll 2 -> 8 edges in flight per wave
    for (; e + 4 < end; e += 8) {
        int s0 = csr[e];
        int s1 = csr[e + 4];
        uint2 v0 = ts64[s0 * 16 + fl];
        uint2 v1 = ts64[s1 * 16 + fl];
        a0 += bflo(v0.x) + bflo(v1.x);
        a1 += bfhi(v0.x) + bfhi(v1.x);
        a2 += bflo(v0.y) + bflo(v1.y);
        a3 += bfhi(v0.y) + bfhi(v1.y);
    }
    if (e < end) {
        uint2 v = ts64[csr[e] * 16 + fl];
        a0 += bflo(v.x); a1 += bfhi(v.x); a2 += bflo(v.y); a3 += bfhi(v.y);
    }
    a0 += __shfl_xor(a0, 16); a1 += __shfl_xor(a1, 16);
    a2 += __shfl_xor(a2, 16); a3 += __shfl_xor(a3, 16);
    a0 += __shfl_xor(a0, 32); a1 += __shfl_xor(a1, 32);
    a2 += __shfl_xor(a2, 32); a3 += __shfl_xor(a3, 32);
    if (q == 0) {
        float dv = dis[node];
        float v0 = fmaxf(a0 * dv + b[4 * fl + 0], 0.f);
        float v1 = fmaxf(a1 * dv + b[4 * fl + 1], 0.f);
        float v2 = fmaxf(a2 * dv + b[4 * fl + 2], 0.f);
        float v3 = fmaxf(a3 * dv + b[4 * fl + 3], 0.f);
        uint2 p;
        p.x = f2bf(v0) | (f2bf(v1) << 16);
        p.y = f2bf(v2) | (f2bf(v3) << 16);
        ((uint2*)hb)[node * 16 + fl] = p;
    }
}

// ---------------------------------------------------------------------------
// Layer 3 projection: t3[row] = dot(h_bf16[row], W3) * dis[row]   (f32 out)
// ---------------------------------------------------------------------------
__global__ void k_gemm3(const unsigned short* __restrict__ hb, const float* __restrict__ W3,
                        const float* __restrict__ dis, float* __restrict__ t3) {
    __shared__ float Ws[64];
    if (threadIdx.x < 64) Ws[threadIdx.x] = W3[threadIdx.x];
    __syncthreads();
    int row = blockIdx.x * 256 + threadIdx.x;
    if (row >= NN) return;
    const uint4* hp = (const uint4*)(hb + row * 64);  // 8 x uint4 = 128 B
    float acc = 0.f;
#pragma unroll
    for (int k = 0; k < 8; ++k) {
        uint4 v = hp[k];
        acc += bflo(v.x) * Ws[8 * k + 0] + bfhi(v.x) * Ws[8 * k + 1]
             + bflo(v.y) * Ws[8 * k + 2] + bfhi(v.y) * Ws[8 * k + 3]
             + bflo(v.z) * Ws[8 * k + 4] + bfhi(v.z) * Ws[8 * k + 5]
             + bflo(v.w) * Ws[8 * k + 6] + bfhi(v.w) * Ws[8 * k + 7];
    }
    t3[row] = acc * dis[row];
}

// Fused layer-3 aggregation + sigmoid. One thread per node, scalar gathers.
__global__ void k_out(const float* __restrict__ t3, const int* __restrict__ rowptr,
                      const int* __restrict__ csr, const float* __restrict__ dis,
                      const float* __restrict__ b3, float* __restrict__ out) {
    int i = blockIdx.x * 256 + threadIdx.x;
    if (i >= NN) return;
    float acc = t3[i];
    float acc1 = 0.f;
    int e = rowptr[i], end = rowptr[i + 1];
    for (; e + 2 <= end; e += 2) {
        acc += t3[csr[e]];
        acc1 += t3[csr[e + 1]];
    }
    if (e < end) acc += t3[csr[e]];
    float z = (acc + acc1) * dis[i] + b3[0];
    out[i] = 1.f / (1.f + __expf(-z));
}

// ---------------------------------------------------------------------------
extern "C" void kernel_launch(void* const* d_in, const int* in_sizes, int n_in,
                              void* d_out, int out_size, void* d_ws, size_t ws_size,
                              hipStream_t stream) {
    const float* x  = (const float*)d_in[0];   // N x 128
    const float* W1 = (const float*)d_in[1];   // 128 x 64
    const float* b1 = (const float*)d_in[2];   // 64
    const float* W2 = (const float*)d_in[3];   // 64 x 64
    const float* b2 = (const float*)d_in[4];   // 64
    const float* W3 = (const float*)d_in[5];   // 64 x 1
    const float* b3 = (const float*)d_in[6];   // 1
    const int*   ei = (const int*)d_in[7];     // 2 x E
    const int* src = ei;
    const int* dst = ei + NE;
    float* out = (float*)d_out;

    // Workspace layout
    unsigned short* TSB = (unsigned short*)d_ws;          // N*64 bf16 (ts)
    unsigned short* HB  = TSB + (size_t)NN * 64;          // N*64 bf16 (h)
    float* dis    = (float*)(HB + (size_t)NN * 64);       // N
    float* t3     = dis + NN;                             // N
    int*   deg    = (int*)(t3 + NN);                      // N
    int*   rowptr = deg + NN;                             // N+1 (+pad)
    int*   cursor = rowptr + NN + 8;                      // N
    int*   bsums  = cursor + NN;                          // 512
    int*   bscan  = bsums + 512;                          // 512
    int*   csr    = bscan + 512;                          // E

    const int nbN = (NN + 255) / 256;   // 391
    const int nbE = (NE + 255) / 256;   // 6250
    const int nbG = (NN + 63) / 64;     // 1563
    const int nbA = (NN + 3) / 4;       // 25000

    // CSR build + normalization
    k_zero_deg<<<nbN, 256, 0, stream>>>(deg);
    k_hist<<<nbE, 256, 0, stream>>>(dst, deg);
    k_bsum<<<nbN, 256, 0, stream>>>(deg, bsums);
    k_scan512<<<1, 512, 0, stream>>>(bsums, bscan);
    k_rowptr<<<nbN, 256, 0, stream>>>(deg, bscan, rowptr, cursor, dis);
    k_build_csr<<<2048, 256, 0, stream>>>(src, dst, cursor, csr);

    // Layer 1
    k_gemm1<<<nbG, 256, 0, stream>>>(x, W1, dis, TSB);
    k_agg_relu<<<nbA, 256, 0, stream>>>(TSB, rowptr, csr, dis, b1, HB);

    // Layer 2
    k_gemm2<<<nbG, 256, 0, stream>>>(HB, W2, dis, TSB);
    k_agg_relu<<<nbA, 256, 0, stream>>>(TSB, rowptr, csr, dis, b2, HB);

    // Layer 3
    k_gemm3<<<nbN, 256, 0, stream>>>(HB, W3, dis, t3);
    k_out<<<nbN, 256, 0, stream>>>(t3, rowptr, csr, dis, b3, out);
}